// Round 6
// baseline (433.969 us; speedup 1.0000x reference)
//
#include <hip/hip_runtime.h>

#define N_NODES 100000
#define N_EDGES 1200000
#define D_IN 256
#define D_OUT 64

#define BUCKET_BITS 7
#define BUCKET_ROWS 128                       // rows per bucket
#define N_BUCKETS   ((N_NODES + BUCKET_ROWS - 1) / BUCKET_ROWS)  // 782

// ---- workspace layout (bytes) ----------------------------------------------
#define OFF_SUPPORT   0u                 // bf16: 100000*64*2 = 12,800,000
#define OFF_ROWSTART  12800000u          // (N_NODES+1)*4 -> padded 400,016
#define OFF_COUNTS    13200016u          // 400,000
#define OFF_BFILL     13600016u          // 782*4 -> padded 4,096
#define OFF_ETMP      13604112u          // 1.2M * 8B = 9,600,000
#define OFF_EDGES     23204112u          // 1.2M * 8B = 9,600,000
#define OFF_BLKSUMS   32804112u          // 512*4
#define WS_NEEDED     32806160u

using bf16x8 = __attribute__((ext_vector_type(8))) short;
using f32x4  = __attribute__((ext_vector_type(4))) float;

static __device__ __forceinline__ ushort f32_to_bf16_rne(float f) {
    unsigned bits = __float_as_uint(f);
    unsigned r = (bits + 0x7FFFu + ((bits >> 16) & 1u)) >> 16;
    return (ushort)r;
}
static __device__ __forceinline__ float bf16_to_f32(ushort u) {
    return __uint_as_float((unsigned)u << 16);
}
static __device__ __forceinline__ unsigned pack2bf(float a, float b) {
    return (unsigned)f32_to_bf16_rne(a) | ((unsigned)f32_to_bf16_rne(b) << 16);
}

// ---------------------------------------------------------------------------
// support(bf16) = X @ W — MFMA 16x16x32 bf16 (unchanged from R4, verified).
// ---------------------------------------------------------------------------
__global__ __launch_bounds__(256, 4) void gemm_xw_mfma(const float* __restrict__ X,
                                                       const float* __restrict__ W,
                                                       ushort* __restrict__ support) {
    __shared__ ushort XsT[4][128][8];
    __shared__ ushort WtT[32][64][8];

    const int t = threadIdx.x;
    const int row0 = blockIdx.x * 128;
    const int lane = t & 63;
    const int w = t >> 6;
    const int lr = lane & 15;
    const int lg = lane >> 4;

#pragma unroll
    for (int p = 0; p < 16; ++p) {
        int idx = t + p * 256;
        int k   = idx >> 4;
        int c4  = idx & 15;
        float4 v = *reinterpret_cast<const float4*>(W + (size_t)k * D_OUT + c4 * 4);
        WtT[k >> 3][c4 * 4 + 0][k & 7] = f32_to_bf16_rne(v.x);
        WtT[k >> 3][c4 * 4 + 1][k & 7] = f32_to_bf16_rne(v.y);
        WtT[k >> 3][c4 * 4 + 2][k & 7] = f32_to_bf16_rne(v.z);
        WtT[k >> 3][c4 * 4 + 3][k & 7] = f32_to_bf16_rne(v.w);
    }

    int  xrow[4], xq[4];
    bool xval[4];
#pragma unroll
    for (int p = 0; p < 4; ++p) {
        int idx = t + p * 256;
        xrow[p] = idx >> 3;
        xq[p]   = idx & 7;
        xval[p] = (row0 + xrow[p]) < N_NODES;
    }

    float4 xreg[4];
#pragma unroll
    for (int p = 0; p < 4; ++p) {
        xreg[p] = make_float4(0.f, 0.f, 0.f, 0.f);
        if (xval[p])
            xreg[p] = *reinterpret_cast<const float4*>(
                X + (size_t)(row0 + xrow[p]) * D_IN + xq[p] * 4);
    }

    f32x4 acc[2][4];
#pragma unroll
    for (int mi = 0; mi < 2; ++mi)
#pragma unroll
        for (int ni = 0; ni < 4; ++ni) acc[mi][ni] = (f32x4){0.f, 0.f, 0.f, 0.f};

    for (int kt = 0; kt < 8; ++kt) {
#pragma unroll
        for (int p = 0; p < 4; ++p) {
            uint2 u;
            u.x = pack2bf(xreg[p].x, xreg[p].y);
            u.y = pack2bf(xreg[p].z, xreg[p].w);
            *reinterpret_cast<uint2*>(&XsT[xq[p] >> 1][xrow[p]][(xq[p] & 1) * 4]) = u;
        }
        __syncthreads();

        if (kt < 7) {
#pragma unroll
            for (int p = 0; p < 4; ++p) {
                if (xval[p])
                    xreg[p] = *reinterpret_cast<const float4*>(
                        X + (size_t)(row0 + xrow[p]) * D_IN + (kt + 1) * 32 + xq[p] * 4);
            }
        }

        bf16x8 a0 = *reinterpret_cast<const bf16x8*>(&XsT[lg][w * 32 + lr][0]);
        bf16x8 a1 = *reinterpret_cast<const bf16x8*>(&XsT[lg][w * 32 + 16 + lr][0]);
#pragma unroll
        for (int ni = 0; ni < 4; ++ni) {
            bf16x8 b = *reinterpret_cast<const bf16x8*>(&WtT[kt * 4 + lg][ni * 16 + lr][0]);
            acc[0][ni] = __builtin_amdgcn_mfma_f32_16x16x32_bf16(a0, b, acc[0][ni], 0, 0, 0);
            acc[1][ni] = __builtin_amdgcn_mfma_f32_16x16x32_bf16(a1, b, acc[1][ni], 0, 0, 0);
        }
        __syncthreads();
    }

#pragma unroll
    for (int mi = 0; mi < 2; ++mi) {
#pragma unroll
        for (int reg = 0; reg < 4; ++reg) {
            int grow = row0 + w * 32 + mi * 16 + lg * 4 + reg;
            if (grow < N_NODES) {
#pragma unroll
                for (int ni = 0; ni < 4; ++ni)
                    support[(size_t)grow * D_OUT + ni * 16 + lr] =
                        f32_to_bf16_rne(acc[mi][ni][reg]);
            }
        }
    }
}

// ---------------------------------------------------------------------------
// CSR build
// ---------------------------------------------------------------------------
__global__ void zero_ints(int* __restrict__ a, int n) {
    int i = blockIdx.x * blockDim.x + threadIdx.x;
    int stride = gridDim.x * blockDim.x;
    for (; i < n; i += stride) a[i] = 0;
}

__global__ void hist_rows(const int* __restrict__ rows, int* __restrict__ counts) {
    int i = blockIdx.x * blockDim.x + threadIdx.x;
    int stride = gridDim.x * blockDim.x;
    for (; i < N_EDGES; i += stride) atomicAdd(&counts[rows[i]], 1);
}

__global__ __launch_bounds__(256) void scan_l1(const int* __restrict__ counts,
                                               int* __restrict__ row_start,
                                               int* __restrict__ blkSums) {
    __shared__ int s[256];
    const int t = threadIdx.x;
    const int i = blockIdx.x * 256 + t;
    int v = (i < N_NODES) ? counts[i] : 0;
    s[t] = v;
    __syncthreads();
#pragma unroll
    for (int off = 1; off < 256; off <<= 1) {
        int x = (t >= off) ? s[t - off] : 0;
        __syncthreads();
        s[t] += x;
        __syncthreads();
    }
    if (i < N_NODES) row_start[i] = s[t] - v;
    if (t == 255) blkSums[blockIdx.x] = s[255];
}

__global__ __launch_bounds__(512) void scan_l2(int* __restrict__ blkSums, int nblk) {
    __shared__ int s[512];
    const int t = threadIdx.x;
    int v = (t < nblk) ? blkSums[t] : 0;
    s[t] = v;
    __syncthreads();
#pragma unroll
    for (int off = 1; off < 512; off <<= 1) {
        int x = (t >= off) ? s[t - off] : 0;
        __syncthreads();
        s[t] += x;
        __syncthreads();
    }
    if (t < nblk) blkSums[t] = s[t] - v;
}

__global__ __launch_bounds__(256) void scan_l3(int* __restrict__ row_start,
                                               const int* __restrict__ blkSums) {
    const int i = blockIdx.x * 256 + threadIdx.x;
    if (i < N_NODES) row_start[i] += blkSums[blockIdx.x];
    if (i == 0) row_start[N_NODES] = N_EDGES;
}

// Phase A: append edges into 782 row-range buckets. Active write tails =
// 782 cachelines (50 KB) -> L2-resident -> stores coalesce in-line before
// writeback (fixes R4's 77 MB scattered WRITE_SIZE).
// Packed: u.x = col (17b) | (row & 127) << 17 ; u.y = val bits.
__global__ void bucket_scatter(const int* __restrict__ rows,
                               const int* __restrict__ cols,
                               const float* __restrict__ vals,
                               const int* __restrict__ row_start,
                               int* __restrict__ bfill,
                               uint2* __restrict__ etmp) {
    int i = blockIdx.x * blockDim.x + threadIdx.x;
    int stride = gridDim.x * blockDim.x;
    for (; i < N_EDGES; i += stride) {
        int r = rows[i];
        int b = r >> BUCKET_BITS;
        int pos = row_start[b << BUCKET_BITS] + atomicAdd(&bfill[b], 1);
        etmp[pos] = make_uint2((unsigned)cols[i] | ((unsigned)(r & (BUCKET_ROWS - 1)) << 17),
                               __float_as_uint(vals[i]));
    }
}

// Phase B: one block per bucket. Reads its span coalesced, scatters into the
// bucket's contiguous ~37 KB final CSR window (L2-hot) using LDS row counters.
__global__ __launch_bounds__(256) void bucket_sort(const uint2* __restrict__ etmp,
                                                   const int* __restrict__ row_start,
                                                   uint2* __restrict__ edge_s) {
    __shared__ int cnt[BUCKET_ROWS];
    const int b = blockIdx.x;
    const int t = threadIdx.x;
    if (t < BUCKET_ROWS) cnt[t] = 0;
    __syncthreads();

    const int r0 = b << BUCKET_BITS;
    const int bstart = row_start[r0];
    const int bend   = row_start[min(r0 + BUCKET_ROWS, N_NODES)];

    for (int e = bstart + t; e < bend; e += 256) {
        uint2 u = etmp[e];
        int lr  = (int)(u.x >> 17) & (BUCKET_ROWS - 1);
        int col = (int)(u.x & 0x1FFFFu);
        int pos = row_start[r0 + lr] + atomicAdd(&cnt[lr], 1);
        edge_s[pos] = make_uint2((unsigned)col, u.y);
    }
}

// ---------------------------------------------------------------------------
// Gather: wave per row, half-wave per edge (lanes 0-31: edge e, 32-63: e+1),
// bf16x2 per lane, unroll 2 -> 4 independent edge gathers in flight.
// ---------------------------------------------------------------------------
__global__ __launch_bounds__(256) void spmm_gather(const uint2* __restrict__ edge_s,
                                                   const int* __restrict__ row_start,
                                                   const ushort* __restrict__ support,
                                                   float* __restrict__ out) {
    const int r = blockIdx.x * 4 + (threadIdx.x >> 6);
    if (r >= N_NODES) return;
    const int lane = threadIdx.x & 63;
    const int h = lane >> 5;        // which edge of the pair
    const int c = lane & 31;        // column pair: cols {2c, 2c+1}

    int e   = row_start[r];
    int end = row_start[r + 1];
    float2 acc = {0.f, 0.f};

    for (; e + 3 < end; e += 4) {
        uint2 p0 = edge_s[e + h];
        uint2 p1 = edge_s[e + 2 + h];
        unsigned s0 = *reinterpret_cast<const unsigned*>(support + (size_t)p0.x * D_OUT + 2 * c);
        unsigned s1 = *reinterpret_cast<const unsigned*>(support + (size_t)p1.x * D_OUT + 2 * c);
        float v0 = __uint_as_float(p0.y);
        float v1 = __uint_as_float(p1.y);
        acc.x = fmaf(v0, bf16_to_f32((ushort)(s0 & 0xFFFFu)), acc.x);
        acc.y = fmaf(v0, bf16_to_f32((ushort)(s0 >> 16)), acc.y);
        acc.x = fmaf(v1, bf16_to_f32((ushort)(s1 & 0xFFFFu)), acc.x);
        acc.y = fmaf(v1, bf16_to_f32((ushort)(s1 >> 16)), acc.y);
    }
    for (int ee = e + h; ee < end; ee += 2) {
        uint2 p = edge_s[ee];
        unsigned s = *reinterpret_cast<const unsigned*>(support + (size_t)p.x * D_OUT + 2 * c);
        float v = __uint_as_float(p.y);
        acc.x = fmaf(v, bf16_to_f32((ushort)(s & 0xFFFFu)), acc.x);
        acc.y = fmaf(v, bf16_to_f32((ushort)(s >> 16)), acc.y);
    }

    acc.x += __shfl_xor(acc.x, 32);
    acc.y += __shfl_xor(acc.y, 32);
    if (h == 0)
        *reinterpret_cast<float2*>(out + (size_t)r * D_OUT + 2 * c) = acc;
}

// ---------------------------------------------------------------------------
// Fallback path (ws too small): zero + atomic scatter from bf16 support.
// ---------------------------------------------------------------------------
__global__ void zero_out(float4* __restrict__ out, int n4) {
    int i = blockIdx.x * blockDim.x + threadIdx.x;
    int stride = gridDim.x * blockDim.x;
    for (; i < n4; i += stride) out[i] = float4{0.0f, 0.0f, 0.0f, 0.0f};
}

__global__ __launch_bounds__(256) void spmm_scatter(const int* __restrict__ rows,
                                                    const int* __restrict__ cols,
                                                    const float* __restrict__ vals,
                                                    const ushort* __restrict__ support,
                                                    float* __restrict__ out,
                                                    int n_edges) {
    const int lane = threadIdx.x & 63;
    const int wave_global = (int)((blockIdx.x * blockDim.x + threadIdx.x) >> 6);
    const int n_waves = (int)((gridDim.x * blockDim.x) >> 6);

    for (int base = wave_global * 64; base < n_edges; base += n_waves * 64) {
        int my_e = base + lane;
        int r = rows[my_e];
        int c = cols[my_e];
        float v = vals[my_e];

        int cnt = min(64, n_edges - base);
        for (int i = 0; i < cnt; ++i) {
            int row = __shfl(r, i);
            int col = __shfl(c, i);
            float val = __shfl(v, i);
            float s = bf16_to_f32(support[(size_t)col * D_OUT + lane]);
            atomicAdd(&out[(size_t)row * D_OUT + lane], val * s);
        }
    }
}

extern "C" void kernel_launch(void* const* d_in, const int* in_sizes, int n_in,
                              void* d_out, int out_size, void* d_ws, size_t ws_size,
                              hipStream_t stream) {
    const float* X      = (const float*)d_in[0];
    const float* W      = (const float*)d_in[1];
    const int*   A_rows = (const int*)d_in[2];
    const int*   A_cols = (const int*)d_in[3];
    const float* A_vals = (const float*)d_in[4];
    float* out = (float*)d_out;

    char* ws = (char*)d_ws;
    ushort* support = (ushort*)(ws + OFF_SUPPORT);

    const int gemm_blocks = (N_NODES + 127) / 128;  // 782

    if (ws_size >= (size_t)WS_NEEDED) {
        int*   row_start = (int*)(ws + OFF_ROWSTART);
        int*   counts    = (int*)(ws + OFF_COUNTS);
        int*   bfill     = (int*)(ws + OFF_BFILL);
        uint2* etmp      = (uint2*)(ws + OFF_ETMP);
        uint2* edge_s    = (uint2*)(ws + OFF_EDGES);
        int*   blkSums   = (int*)(ws + OFF_BLKSUMS);

        const int nblk_scan = (N_NODES + 255) / 256;  // 391

        // CSR build
        zero_ints<<<256, 256, 0, stream>>>(counts, (400000 + 4096) / 4);  // counts+bfill
        hist_rows<<<1024, 256, 0, stream>>>(A_rows, counts);
        scan_l1<<<nblk_scan, 256, 0, stream>>>(counts, row_start, blkSums);
        scan_l2<<<1, 512, 0, stream>>>(blkSums, nblk_scan);
        scan_l3<<<nblk_scan, 256, 0, stream>>>(row_start, blkSums);
        bucket_scatter<<<1024, 256, 0, stream>>>(A_rows, A_cols, A_vals, row_start,
                                                 bfill, etmp);
        bucket_sort<<<N_BUCKETS, 256, 0, stream>>>(etmp, row_start, edge_s);

        // support = bf16(X @ W)  (MFMA)
        gemm_xw_mfma<<<gemm_blocks, 256, 0, stream>>>(X, W, support);

        // out = A @ support (gather, no atomics)
        spmm_gather<<<(N_NODES + 3) / 4, 256, 0, stream>>>(edge_s, row_start,
                                                           support, out);
    } else {
        int n4 = (N_NODES * D_OUT) / 4;
        zero_out<<<2048, 256, 0, stream>>>((float4*)out, n4);
        gemm_xw_mfma<<<gemm_blocks, 256, 0, stream>>>(X, W, support);
        int chunks = N_EDGES / 64;
        spmm_scatter<<<(chunks + 3) / 4, 256, 0, stream>>>(A_rows, A_cols, A_vals,
                                                           support, out, N_EDGES);
    }
}